// Round 1
// baseline (719.507 us; speedup 1.0000x reference)
//
#include <hip/hip_runtime.h>
#include <stdint.h>

#define NB   4096   // batch rows
#define LDIM 4096   // latent dim
#define KK   10     // k
#define TPB  256

__global__ __launch_bounds__(TPB) void topk_sparsemax(
    const float* __restrict__ logits,
    float* __restrict__ bv,      // [NB, KK, LDIM]
    float* __restrict__ distr,   // [NB, KK]
    float* __restrict__ ent)     // [1]
{
    __shared__ unsigned long long s_red[4];
    __shared__ float s_wsum[4];
    __shared__ float s_csmall[KK];  // k smallest |logit| (ascending)
    __shared__ int   s_pos[KK];     // their indices
    __shared__ int   s_sign[KK];    // base bit at those positions (logit > 0)
    __shared__ int   s_bestm[KK];   // chosen flip-subset masks (cost ascending)
    __shared__ float s_cost[KK];    // their costs

    const int b    = blockIdx.x;
    const int t    = threadIdx.x;
    const int lane = t & 63;
    const int wv   = t >> 6;
    const float* __restrict__ row = logits + (size_t)b * LDIM;

    // ---- load 16 logits/thread, coalesced: element i -> col ((i>>2)<<10) + 4t + (i&3)
    float vals[16];
#pragma unroll
    for (int q = 0; q < 4; q++) {
        const float4 f = *(const float4*)(row + (q << 10) + (t << 2));
        vals[q*4+0] = f.x; vals[q*4+1] = f.y; vals[q*4+2] = f.z; vals[q*4+3] = f.w;
    }

    // ---- S0 = sum of positive logits (block reduce; order-insensitive, S0 cancels in distr)
    float s0 = 0.f;
#pragma unroll
    for (int i = 0; i < 16; i++) s0 += vals[i] > 0.f ? vals[i] : 0.f;
#pragma unroll
    for (int off = 1; off < 64; off <<= 1) s0 += __shfl_xor(s0, off, 64);
    if (lane == 0) s_wsum[wv] = s0;
    __syncthreads();
    const float S0 = (s_wsum[0] + s_wsum[1]) + (s_wsum[2] + s_wsum[3]);

    // ---- stage 1: 10 smallest |logit| with (cost, index) lexicographic order
    // packed u64 = (cost_bits << 32) | (idx << 1) | sign ; min == top_k(-cost) order
    unsigned int taken = 0u;
    for (int c = 0; c < KK; c++) {
        unsigned long long best = ~0ull;
#pragma unroll
        for (int i = 0; i < 16; i++) {
            if (!(taken & (1u << i))) {
                const float val  = vals[i];
                const float cost = fabsf(val);
                const int   idx  = ((i >> 2) << 10) + (t << 2) + (i & 3);
                const unsigned long long pk =
                    ((unsigned long long)__float_as_uint(cost) << 32)
                    | (unsigned)((idx << 1) | (val > 0.f ? 1 : 0));
                if (pk < best) best = pk;
            }
        }
#pragma unroll
        for (int off = 1; off < 64; off <<= 1) {
            const unsigned long long o = __shfl_xor(best, off, 64);
            if (o < best) best = o;
        }
        if (lane == 0) s_red[wv] = best;
        __syncthreads();
        unsigned long long w = s_red[0];
        if (s_red[1] < w) w = s_red[1];
        if (s_red[2] < w) w = s_red[2];
        if (s_red[3] < w) w = s_red[3];
        const unsigned lo = (unsigned)w;
        const int widx = (int)(lo >> 1);
        if (t == 0) {
            s_pos[c]    = widx;
            s_sign[c]   = (int)(lo & 1u);
            s_csmall[c] = __uint_as_float((unsigned)(w >> 32));
        }
        const int rem = widx & 1023;
        if ((rem >> 2) == t) taken |= 1u << (((widx >> 10) << 2) | (rem & 3));
        __syncthreads();
    }

    // ---- stage 2: 1024 subset sums (ascending-bit accumulation == einsum rounding),
    //      then 10 smallest with (sum, subset-index) order
    float csm[KK];
#pragma unroll
    for (int j = 0; j < KK; j++) csm[j] = s_csmall[j];
    float sums[4];
#pragma unroll
    for (int i = 0; i < 4; i++) {
        const int m = (t << 2) | i;
        float acc = 0.f;
#pragma unroll
        for (int j = 0; j < KK; j++) acc += (m & (1 << j)) ? csm[j] : 0.f;
        sums[i] = acc;
    }
    unsigned int taken2 = 0u;
    for (int c = 0; c < KK; c++) {
        unsigned long long best = ~0ull;
#pragma unroll
        for (int i = 0; i < 4; i++) {
            if (!(taken2 & (1u << i))) {
                const unsigned long long pk =
                    ((unsigned long long)__float_as_uint(sums[i]) << 32)
                    | (unsigned)((t << 2) | i);
                if (pk < best) best = pk;
            }
        }
#pragma unroll
        for (int off = 1; off < 64; off <<= 1) {
            const unsigned long long o = __shfl_xor(best, off, 64);
            if (o < best) best = o;
        }
        if (lane == 0) s_red[wv] = best;
        __syncthreads();
        unsigned long long w = s_red[0];
        if (s_red[1] < w) w = s_red[1];
        if (s_red[2] < w) w = s_red[2];
        if (s_red[3] < w) w = s_red[3];
        const int wm = (int)(unsigned)w;
        if (t == 0) {
            s_bestm[c] = wm;
            s_cost[c]  = __uint_as_float((unsigned)(w >> 32));
        }
        if ((wm >> 2) == t) taken2 |= 1u << (wm & 3);
        __syncthreads();
    }

    // ---- sparsemax over scores[c] = S0 - cost_c (already sorted descending) + entropy
    if (t == 0) {
        float z[KK];
#pragma unroll
        for (int c = 0; c < KK; c++) z[c] = S0 - s_cost[c];
        float acc = 0.f; int ks = 0;
#pragma unroll
        for (int r = 1; r <= KK; r++) {
            acc += z[r-1];
            if (1.f + (float)r * z[r-1] > acc) ks++;
        }
        float acc2 = 0.f;
#pragma unroll
        for (int r = 0; r < KK; r++) if (r < ks) acc2 += z[r];
        const float tau = (acc2 - 1.f) / (float)ks;
        float entl = 0.f;
        float* drow = distr + b * KK;
#pragma unroll
        for (int c = 0; c < KK; c++) {
            float p = z[c] - tau;
            p = p > 0.f ? p : 0.f;
            drow[c] = p;
            if (p > 0.f) entl -= p * logf(p);
        }
        atomicAdd(ent, entl * (1.0f / (float)NB));
    }

    // ---- bulk bv write: base row 10x, coalesced float4
    float4 base4[4];
#pragma unroll
    for (int q = 0; q < 4; q++) {
        base4[q].x = vals[q*4+0] > 0.f ? 1.f : 0.f;
        base4[q].y = vals[q*4+1] > 0.f ? 1.f : 0.f;
        base4[q].z = vals[q*4+2] > 0.f ? 1.f : 0.f;
        base4[q].w = vals[q*4+3] > 0.f ? 1.f : 0.f;
    }
    float* out0 = bv + (size_t)b * (KK * LDIM);
#pragma unroll
    for (int c = 0; c < KK; c++) {
        float* orow = out0 + c * LDIM + (t << 2);
#pragma unroll
        for (int q = 0; q < 4; q++)
            *(float4*)(orow + (q << 10)) = base4[q];
    }

    // ---- flip fixup: barrier drains stores, then overwrite <=100 scattered elems
    __syncthreads();
    if (t < KK * KK) {
        const int c = t / KK, j = t % KK;
        if ((s_bestm[c] >> j) & 1)
            out0[c * LDIM + s_pos[j]] = s_sign[j] ? 0.f : 1.f;
    }
}

extern "C" void kernel_launch(void* const* d_in, const int* in_sizes, int n_in,
                              void* d_out, int out_size, void* d_ws, size_t ws_size,
                              hipStream_t stream)
{
    const float* logits = (const float*)d_in[0];
    float* out   = (float*)d_out;
    float* bv    = out;
    float* distr = out + (size_t)NB * KK * LDIM;
    float* ent   = distr + (size_t)NB * KK;
    // harness poisons d_out with 0xAA before timed replays; entropy is accumulated
    hipMemsetAsync(ent, 0, sizeof(float), stream);
    topk_sparsemax<<<dim3(NB), dim3(TPB), 0, stream>>>(logits, bv, distr, ent);
}